// Round 2
// baseline (1499.973 us; speedup 1.0000x reference)
//
#include <hip/hip_runtime.h>
#include <hip/hip_cooperative_groups.h>
#include <math.h>

namespace cg = cooperative_groups;

#define GLN_EPS 0.001f
#define NBLK 256

__device__ __forceinline__ float clipf_(float v) {
    return fminf(fmaxf(v, GLN_EPS), 1.0f - GLN_EPS);
}
__device__ __forceinline__ float logitf_(float p) {
    return logf(p) - log1pf(-p);
}
__device__ __forceinline__ float sigclip_logit(float z) {
    // logit(clip(sigmoid(z))) — replicate reference op sequence
    float s = 1.0f / (1.0f + expf(-z));
    s = clipf_(s);
    return logf(s) - log1pf(-s);
}

struct GlnArgs {
    const float *side, *W0, *N0, *O0, *B0;
    const float *W1, *N1, *O1, *B1;
    const float *W2, *N2, *O2, *B2;
    float* ws;
    float* out;
};

// ws layout (floats): [0..1023] acc0, [1024..1535] acc1, [1536..1538] g0,g1,g2 (int bits)

__global__ __launch_bounds__(256) void gln_fused(GlnArgs a)
{
    __shared__ float sred[16 * 64];   // 4 KB column-reduction scratch (phases 1,2)
    __shared__ float red8[4][8];      // gating / final reduction

    const int bid = blockIdx.x, tid = threadIdx.x;
    float* ws = a.ws;

    // ---------------- Phase 0: gating indices (blocks 0-2) + zero acc (block 3)
    if (bid < 3) {
        const float* __restrict__ N = (bid == 0) ? a.N0 : (bid == 1) ? a.N1 : a.N2;
        const float* __restrict__ O = (bid == 0) ? a.O0 : (bid == 1) ? a.O1 : a.O2;
        float p[8];
#pragma unroll
        for (int k = 0; k < 8; ++k) p[k] = 0.0f;
        for (int i = tid; i < 1024; i += 256) {
            const float s = a.side[i];
            const float4* n4 = reinterpret_cast<const float4*>(N + (size_t)i * 8);
            const float4 u = n4[0], v = n4[1];
            p[0] += s * u.x; p[1] += s * u.y; p[2] += s * u.z; p[3] += s * u.w;
            p[4] += s * v.x; p[5] += s * v.y; p[6] += s * v.z; p[7] += s * v.w;
        }
        const int lane = tid & 63, wid = tid >> 6;
#pragma unroll
        for (int k = 0; k < 8; ++k) {
            float v = p[k];
#pragma unroll
            for (int off = 32; off > 0; off >>= 1) v += __shfl_down(v, off);
            if (lane == 0) red8[wid][k] = v;
        }
        __syncthreads();
        if (tid == 0) {
            int g = 0;
#pragma unroll
            for (int k = 0; k < 8; ++k) {
                const float d = red8[0][k] + red8[1][k] + red8[2][k] + red8[3][k];
                if (d > O[k]) g |= 1 << (7 - k);
            }
            reinterpret_cast<int*>(ws)[1536 + bid] = g;
        }
    } else if (bid == 3) {
        for (int i = tid; i < 1536; i += 256) ws[i] = 0.0f;
    }
    cg::this_grid().sync();

    // ---------------- Phase 1: acc0[j] = sum_i x0[i] * W0[g0][i][j], j in [0,1024)
    // 16 colchunks x 16 rowchunks = 256 blocks; 16 atomics per output address.
    {
        const int g0 = reinterpret_cast<const int*>(ws)[1536];
        const float lb = logitf_(a.B0[0]);
        const size_t base = (size_t)g0 * (1025u * 1024u);
        const int colchunk = bid & 15;
        const int c16 = tid & 15, r16 = tid >> 4;
        const int rowid = ((bid >> 4) << 4) | r16;      // [0,256)
        const int col = colchunk * 64 + c16 * 4;

        float4 acc = make_float4(0.f, 0.f, 0.f, 0.f);
        for (int i = rowid; i < 1025; i += 256) {
            const float xi = (i == 0) ? lb : clipf_(a.side[i - 1]);
            const float4 w = *reinterpret_cast<const float4*>(a.W0 + base + (size_t)i * 1024u + col);
            acc.x += xi * w.x; acc.y += xi * w.y; acc.z += xi * w.z; acc.w += xi * w.w;
        }
        *reinterpret_cast<float4*>(&sred[r16 * 64 + c16 * 4]) = acc;
        __syncthreads();
        if (tid < 64) {
            float s = 0.0f;
#pragma unroll
            for (int r = 0; r < 16; ++r) s += sred[r * 64 + tid];
            atomicAdd(&ws[colchunk * 64 + tid], s);
        }
    }
    cg::this_grid().sync();

    // ---------------- Phase 2: acc1[j] = sum_i x1[i] * W1[g1][i][j], j in [0,512)
    // 8 colchunks x 32 rowchunks = 256 blocks; 32 atomics per output address.
    {
        const int g1 = reinterpret_cast<const int*>(ws)[1537];
        const float lb = logitf_(a.B1[0]);
        const size_t base = (size_t)g1 * (1025u * 512u);
        const int colchunk = bid & 7;
        const int c16 = tid & 15, r16 = tid >> 4;
        const int rowid = ((bid >> 3) << 4) | r16;      // [0,512)
        const int col = colchunk * 64 + c16 * 4;

        float4 acc = make_float4(0.f, 0.f, 0.f, 0.f);
        for (int i = rowid; i < 1025; i += 512) {
            const float xi = (i == 0) ? lb : sigclip_logit(ws[i - 1]);
            const float4 w = *reinterpret_cast<const float4*>(a.W1 + base + (size_t)i * 512u + col);
            acc.x += xi * w.x; acc.y += xi * w.y; acc.z += xi * w.z; acc.w += xi * w.w;
        }
        __syncthreads();   // sred reuse safety (phase-1 readers done)
        *reinterpret_cast<float4*>(&sred[r16 * 64 + c16 * 4]) = acc;
        __syncthreads();
        if (tid < 64) {
            float s = 0.0f;
#pragma unroll
            for (int r = 0; r < 16; ++r) s += sred[r * 64 + tid];
            atomicAdd(&ws[1024 + colchunk * 64 + tid], s);
        }
    }
    cg::this_grid().sync();

    // ---------------- Phase 3: out = clip(sigmoid(x2 . W2[g2][:,0])), block 0 only
    if (bid == 0) {
        const int g2 = reinterpret_cast<const int*>(ws)[1538];
        const float lb = logitf_(a.B2[0]);
        const size_t base = (size_t)g2 * 513u;
        float partial = 0.0f;
        for (int i = tid; i < 513; i += 256) {
            const float xi = (i == 0) ? lb : sigclip_logit(ws[1024 + i - 1]);
            partial += xi * a.W2[base + i];
        }
#pragma unroll
        for (int off = 32; off > 0; off >>= 1) partial += __shfl_down(partial, off);
        __syncthreads();   // red8 reuse safety
        if ((tid & 63) == 0) red8[tid >> 6][0] = partial;
        __syncthreads();
        if (tid == 0) {
            const float z = red8[0][0] + red8[1][0] + red8[2][0] + red8[3][0];
            a.out[0] = clipf_(1.0f / (1.0f + expf(-z)));
        }
    }
}

extern "C" void kernel_launch(void* const* d_in, const int* in_sizes, int n_in,
                              void* d_out, int out_size, void* d_ws, size_t ws_size,
                              hipStream_t stream) {
    GlnArgs a;
    a.side = (const float*)d_in[0];
    a.W0 = (const float*)d_in[1];  a.N0 = (const float*)d_in[2];
    a.O0 = (const float*)d_in[3];  a.B0 = (const float*)d_in[4];
    a.W1 = (const float*)d_in[5];  a.N1 = (const float*)d_in[6];
    a.O1 = (const float*)d_in[7];  a.B1 = (const float*)d_in[8];
    a.W2 = (const float*)d_in[9];  a.N2 = (const float*)d_in[10];
    a.O2 = (const float*)d_in[11]; a.B2 = (const float*)d_in[12];
    a.ws  = (float*)d_ws;
    a.out = (float*)d_out;

    void* params[] = { &a };
    hipLaunchCooperativeKernel(reinterpret_cast<void*>(gln_fused),
                               dim3(NBLK), dim3(256), params, 0, stream);
}

// Round 3
// 1364.879 us; speedup vs baseline: 1.0990x; 1.0990x over previous
//
#include <hip/hip_runtime.h>
#include <math.h>

#define GLN_EPS 0.001f

__device__ __forceinline__ float clipf_(float v) {
    return fminf(fmaxf(v, GLN_EPS), 1.0f - GLN_EPS);
}
__device__ __forceinline__ float logitf_(float p) {
    return logf(p) - log1pf(-p);
}
__device__ __forceinline__ float sigclip_logit(float z) {
    // logit(clip(sigmoid(z))) — replicate reference op sequence
    float s = 1.0f / (1.0f + expf(-z));
    s = clipf_(s);
    return logf(s) - log1pf(-s);
}

// ws layout: float ws[0..1023]   = acc0 (layer-0 pre-sigmoid)
//            float ws[1024..1535]= acc1 (layer-1 pre-sigmoid)
//            int   ws[1536..1538]= gating indices g0,g1,g2
//            int   ws[1540]      = gemv1 block-completion counter

// ---------------- Kernel 1: gating indices (blocks 0-2), zero acc+counter (block 3)
__global__ __launch_bounds__(256) void gln_prep(
    const float* __restrict__ side,
    const float* __restrict__ N0, const float* __restrict__ O0,
    const float* __restrict__ N1, const float* __restrict__ O1,
    const float* __restrict__ N2, const float* __restrict__ O2,
    float* __restrict__ ws)
{
    const int bid = blockIdx.x, tid = threadIdx.x;
    if (bid == 3) {
        for (int i = tid; i < 1536; i += 256) ws[i] = 0.0f;
        if (tid == 0) reinterpret_cast<int*>(ws)[1540] = 0;
        return;
    }
    const float* __restrict__ N = (bid == 0) ? N0 : (bid == 1) ? N1 : N2;
    const float* __restrict__ O = (bid == 0) ? O0 : (bid == 1) ? O1 : O2;

    float p[8];
#pragma unroll
    for (int k = 0; k < 8; ++k) p[k] = 0.0f;
    for (int i = tid; i < 1024; i += 256) {
        const float s = side[i];
        const float4* n4 = reinterpret_cast<const float4*>(N + (size_t)i * 8);
        const float4 u = n4[0], v = n4[1];
        p[0] += s * u.x; p[1] += s * u.y; p[2] += s * u.z; p[3] += s * u.w;
        p[4] += s * v.x; p[5] += s * v.y; p[6] += s * v.z; p[7] += s * v.w;
    }
    __shared__ float red8[4][8];
    const int lane = tid & 63, wid = tid >> 6;
#pragma unroll
    for (int k = 0; k < 8; ++k) {
        float v = p[k];
#pragma unroll
        for (int off = 32; off > 0; off >>= 1) v += __shfl_down(v, off);
        if (lane == 0) red8[wid][k] = v;
    }
    __syncthreads();
    if (tid == 0) {
        int g = 0;
#pragma unroll
        for (int k = 0; k < 8; ++k) {
            const float d = red8[0][k] + red8[1][k] + red8[2][k] + red8[3][k];
            if (d > O[k]) g |= 1 << (7 - k);
        }
        reinterpret_cast<int*>(ws)[1536 + bid] = g;
    }
}

// ---------------- Kernel 2: acc0[j] = sum_i x0[i] * W0[g0][i][j], j in [0,1024)
// 256 blocks = 16 colchunks x 16 rowchunks; LDS reduce; 16 atomics/address.
__global__ __launch_bounds__(256) void gln_gemv0(
    const float* __restrict__ side,
    const float* __restrict__ W0,
    const float* __restrict__ B0,
    float* __restrict__ ws)
{
    __shared__ float sred[16 * 64];
    const int bid = blockIdx.x, tid = threadIdx.x;
    const int g0 = reinterpret_cast<const int*>(ws)[1536];
    const float lb = logitf_(B0[0]);
    const size_t base = (size_t)g0 * (1025u * 1024u);
    const int colchunk = bid & 15;
    const int c16 = tid & 15, r16 = tid >> 4;
    const int rowid = ((bid >> 4) << 4) | r16;          // [0,256)
    const int col = colchunk * 64 + c16 * 4;

    float4 acc = make_float4(0.f, 0.f, 0.f, 0.f);
    for (int i = rowid; i < 1025; i += 256) {
        const float xi = (i == 0) ? lb : clipf_(side[i - 1]);
        const float4 w = *reinterpret_cast<const float4*>(W0 + base + (size_t)i * 1024u + col);
        acc.x += xi * w.x; acc.y += xi * w.y; acc.z += xi * w.z; acc.w += xi * w.w;
    }
    *reinterpret_cast<float4*>(&sred[r16 * 64 + c16 * 4]) = acc;
    __syncthreads();
    if (tid < 64) {
        float s = 0.0f;
#pragma unroll
        for (int r = 0; r < 16; ++r) s += sred[r * 64 + tid];
        atomicAdd(&ws[colchunk * 64 + tid], s);
    }
}

// ---------------- Kernel 3: acc1 GEMV + (last block) final layer
// 256 blocks = 8 colchunks x 32 rowchunks; LDS reduce; 32 atomics/address.
__global__ __launch_bounds__(256) void gln_gemv1_final(
    const float* __restrict__ W1,
    const float* __restrict__ B1,
    const float* __restrict__ W2,
    const float* __restrict__ B2,
    float* __restrict__ ws,
    float* __restrict__ out)
{
    __shared__ float sred[16 * 64];
    __shared__ int is_last_s;
    const int bid = blockIdx.x, tid = threadIdx.x;
    const int g1 = reinterpret_cast<const int*>(ws)[1537];
    const float lb = logitf_(B1[0]);
    const size_t base = (size_t)g1 * (1025u * 512u);
    const int colchunk = bid & 7;
    const int c16 = tid & 15, r16 = tid >> 4;
    const int rowid = ((bid >> 3) << 4) | r16;          // [0,512)
    const int col = colchunk * 64 + c16 * 4;

    float4 acc = make_float4(0.f, 0.f, 0.f, 0.f);
    for (int i = rowid; i < 1025; i += 512) {
        const float xi = (i == 0) ? lb : sigclip_logit(ws[i - 1]);
        const float4 w = *reinterpret_cast<const float4*>(W1 + base + (size_t)i * 512u + col);
        acc.x += xi * w.x; acc.y += xi * w.y; acc.z += xi * w.z; acc.w += xi * w.w;
    }
    *reinterpret_cast<float4*>(&sred[r16 * 64 + c16 * 4]) = acc;
    __syncthreads();
    if (tid < 64) {
        float s = 0.0f;
#pragma unroll
        for (int r = 0; r < 16; ++r) s += sred[r * 64 + tid];
        atomicAdd(&ws[1024 + colchunk * 64 + tid], s);
    }

    // ---- last-block-finishes pattern: the 256th block to complete does layer 2
    __threadfence();                       // release our acc1 atomics
    if (tid == 0) {
        const int old = atomicAdd(&reinterpret_cast<int*>(ws)[1540], 1);
        is_last_s = (old == (int)gridDim.x - 1);
    }
    __syncthreads();
    if (!is_last_s) return;
    __threadfence();                       // acquire everyone else's acc1 atomics

    const int g2 = reinterpret_cast<const int*>(ws)[1538];
    const size_t b2 = (size_t)g2 * 513u;
    const float lb2 = logitf_(B2[0]);
    float partial = 0.0f;
    for (int i = tid; i < 513; i += 256) {
        float xi;
        if (i == 0) xi = lb2;
        else {
            const float z = __hip_atomic_load(&ws[1024 + i - 1], __ATOMIC_RELAXED,
                                              __HIP_MEMORY_SCOPE_AGENT);
            xi = sigclip_logit(z);
        }
        partial += xi * W2[b2 + i];
    }
#pragma unroll
    for (int off = 32; off > 0; off >>= 1) partial += __shfl_down(partial, off);
    __syncthreads();                       // sred reuse safety
    if ((tid & 63) == 0) sred[tid >> 6] = partial;
    __syncthreads();
    if (tid == 0) {
        const float z = sred[0] + sred[1] + sred[2] + sred[3];
        out[0] = clipf_(1.0f / (1.0f + expf(-z)));
    }
}

extern "C" void kernel_launch(void* const* d_in, const int* in_sizes, int n_in,
                              void* d_out, int out_size, void* d_ws, size_t ws_size,
                              hipStream_t stream) {
    const float* side = (const float*)d_in[0];
    const float* W0   = (const float*)d_in[1];
    const float* N0   = (const float*)d_in[2];
    const float* O0   = (const float*)d_in[3];
    const float* B0   = (const float*)d_in[4];
    const float* W1   = (const float*)d_in[5];
    const float* N1   = (const float*)d_in[6];
    const float* O1   = (const float*)d_in[7];
    const float* B1   = (const float*)d_in[8];
    const float* W2   = (const float*)d_in[9];
    const float* N2   = (const float*)d_in[10];
    const float* O2   = (const float*)d_in[11];
    const float* B2   = (const float*)d_in[12];
    float* out = (float*)d_out;
    float* ws  = (float*)d_ws;

    hipLaunchKernelGGL(gln_prep,        dim3(4),   dim3(256), 0, stream,
                       side, N0, O0, N1, O1, N2, O2, ws);
    hipLaunchKernelGGL(gln_gemv0,       dim3(256), dim3(256), 0, stream, side, W0, B0, ws);
    hipLaunchKernelGGL(gln_gemv1_final, dim3(256), dim3(256), 0, stream,
                       W1, B1, W2, B2, ws, out);
}